// Round 5
// baseline (179.961 us; speedup 1.0000x reference)
//
#include <hip/hip_runtime.h>
#include <math.h>

#define NPTS 131072
#define KCOMP 256
#define DIM 32
#define NREAL 560                 // 528 tight-packed quad + 32 linear
#define NCH 18                    // 32-feature chunks: 17 full + 1 half (16)
#define PSIF_BYTES 294912         // 18 chunks * 1024 granules * 16 B
#define WS_NEED (PSIF_BYTES + KCOMP * 4)

typedef __attribute__((ext_vector_type(8))) short short8;
typedef __attribute__((ext_vector_type(16))) float f32x16;

__device__ __forceinline__ unsigned short f2bf(float v) {
    unsigned u = __float_as_uint(v);
    u += 0x7fffu + ((u >> 16) & 1u);   // RNE
    return (unsigned short)(u >> 16);
}

// pack two f32 -> two bf16 (lo | hi<<16). RTN (+0x8000) + byte-perm: 3 ops.
__device__ __forceinline__ unsigned pkbf(float lo, float hi) {
#if __has_builtin(__builtin_amdgcn_perm)
    const unsigned a = __float_as_uint(hi) + 0x8000u;
    const unsigned b = __float_as_uint(lo) + 0x8000u;
    return __builtin_amdgcn_perm(a, b, 0x07060302u);
#else
    return (unsigned)f2bf(lo) | ((unsigned)f2bf(hi) << 16);
#endif
}

// async global->LDS DMA, 16 B/lane; LDS dest = wave-uniform base + lane*16.
__device__ __forceinline__ void dma16(const uint4* g, uint4* s) {
    __builtin_amdgcn_global_load_lds(
        (const __attribute__((address_space(1))) void*)g,
        (__attribute__((address_space(3))) void*)s, 16, 0, 0);
}

// counted-vmcnt barrier: DMA for chunk C+2 stays in flight across it.
template<int N>
__device__ __forceinline__ void waitbar() {
    if constexpr (N == 2)
        asm volatile("s_waitcnt vmcnt(2)\ns_barrier" ::: "memory");
    else if constexpr (N == 1)
        asm volatile("s_waitcnt vmcnt(1)\ns_barrier" ::: "memory");
    else
        asm volatile("s_waitcnt vmcnt(0)\ns_barrier" ::: "memory");
}

// ---- compile-time feature decode: TIGHT triangular packing ----------------
// p in [0,528): (d,f) pairs, f>=d, row-major (row d has 32-d entries).
// p in [528,560): linear features (index p-528).
constexpr int PfxT(int d) { return 32 * d - (d * (d - 1)) / 2; }
constexpr int rowT(int p) { int d = 0; while (d < 31 && PfxT(d + 1) <= p) ++d; return d; }
constexpr int colT(int p) { return rowT(p) + (p - PfxT(rowT(p))); }

template<int P, int J>
__device__ __forceinline__ float genOne(const float (&x)[DIM]) {
    constexpr int p = P + J;
    if constexpr (p >= NREAL) {
        return 0.f;
    } else if constexpr (p >= 528) {
        return x[p - 528];
    } else {
        constexpr int d = rowT(p);
        constexpr int f = colT(p);
        static_assert(d >= 0 && d < 32 && f >= d && f < 32, "bad feature map");
        return x[d] * x[f];
    }
}

// ---------------------------------------------------------------------------
// Precompute: Psi column k scattered into frag-ordered PsiF (bf16), kc2 fp32.
// (unchanged layout; consumed 32 features per chunk by the main kernel)
// ---------------------------------------------------------------------------
__global__ __launch_bounds__(256) void gmm_pre(
    const float* __restrict__ S,
    const float* __restrict__ centers,
    const float* __restrict__ weights,
    unsigned short* __restrict__ PsiF,
    float* __restrict__ kc2)
{
    __shared__ float Sl[DIM][DIM + 1];
    __shared__ float As[DIM][DIM + 1];
    __shared__ float cl[DIM], ml[DIM];
    __shared__ float red[256];

    const int k = blockIdx.x, tid = threadIdx.x;

    for (int idx = tid; idx < DIM * DIM; idx += 256)
        Sl[idx >> 5][idx & 31] = S[(size_t)k * DIM * DIM + idx];
    if (tid < DIM) cl[tid] = centers[k * DIM + tid];
    __syncthreads();

    // A = S S^T
    for (int idx = tid; idx < DIM * DIM; idx += 256) {
        const int d = idx >> 5, f = idx & 31;
        float a = 0.f;
#pragma unroll
        for (int e = 0; e < DIM; ++e) a = fmaf(Sl[d][e], Sl[f][e], a);
        As[d][f] = a;
    }
    __syncthreads();

    if (tid < DIM) {
        float mv = 0.f;
#pragma unroll
        for (int f = 0; f < DIM; ++f) mv = fmaf(As[tid][f], cl[f], mv);
        ml[tid] = mv;
    }
    __syncthreads();

    // scatter Psi column k into frag positions (reads As diag+upper, ml).
    for (int p = tid; p < NREAL; p += 256) {
        float val;
        if (p < 528) {
            int d = 0, pr = 0;
            while (pr + (32 - d) <= p) { pr += (32 - d); ++d; }
            const int f = d + (p - pr);
            val = (f == d) ? -0.5f * As[d][d] : -As[d][f];
        } else {
            val = ml[p - 528];
        }
        const int c = p >> 6, kk = p & 63;
        const int s = kk >> 4, qq = (kk >> 3) & 1, j = kk & 7;
        const int ct = k >> 5, ll = qq * 32 + (k & 31);
        const int g = c * 2048 + (s * 8 + ct) * 64 + ll;
        PsiF[(size_t)g * 8 + j] = f2bf(val);
    }

    red[tid] = fabsf(weights[tid]);          // K == 256 == blockDim
    __syncthreads();                          // also fences As/ml reads above
    for (int off = 128; off > 0; off >>= 1) {
        if (tid < off) red[tid] += red[tid + off];
        __syncthreads();
    }
    const float wsum = red[0];

    // SPD Gaussian elimination: 1 barrier/step, logdet(A) = sum log(pivot_j).
    for (int j = 0; j < DIM - 1; ++j) {
        const float inv = 1.0f / As[j][j];
        for (int idx = tid; idx < DIM * DIM; idx += 256) {
            const int r = idx >> 5, c = idx & 31;
            if (r > j && c > j)
                As[r][c] = fmaf(-As[r][j] * inv, As[j][c], As[r][c]);
        }
        __syncthreads();
    }

    if (tid < DIM) red[tid] = __logf(As[tid][tid]);   // pivots > 0 (SPD)
    __syncthreads();
    if (tid == 0) {
        float sl = 0.f;
        for (int j = 0; j < DIM; ++j) sl += red[j];
        float cac = 0.f;
        for (int d2 = 0; d2 < DIM; ++d2) cac = fmaf(ml[d2], cl[d2], cac);
        kc2[k] = __logf(fabsf(weights[k])) - __logf(wsum + 1e-30f)
               + 0.5f * sl - 0.5f * cac;
    }
}

// ---------------------------------------------------------------------------
// Main MFMA kernel v5: A-fragments generated DIRECTLY IN REGISTERS (no sA,
// no gen->LDS round trip): lane l of wave rb consumes features
// C*32 + s*16 + (l>>5)*8 + j of row rb*32+(l&31), which is exactly what the
// thread can compute from its own x. B is 3-deep buffered with counted-vmcnt
// barriers (DMA for chunk C+2 in flight across the end-of-C barrier; never
// vmcnt(0) in steady state). Block = 64 rows x 256 cols, 512 thr, wave tile
// 32r x 64c, acc = 2 x f32x16 = 32 AGPR -> ~4 waves/SIMD, 2 blocks/CU.
// LDS = 3 x 16 KB = 48 KB.
// ---------------------------------------------------------------------------
template<int BASE>
__device__ __forceinline__ uint4 packFrag(const float (&x)[DIM]) {
    float v[8];
    v[0] = genOne<BASE, 0>(x); v[1] = genOne<BASE, 1>(x);
    v[2] = genOne<BASE, 2>(x); v[3] = genOne<BASE, 3>(x);
    v[4] = genOne<BASE, 4>(x); v[5] = genOne<BASE, 5>(x);
    v[6] = genOne<BASE, 6>(x); v[7] = genOne<BASE, 7>(x);
    uint4 u;
    u.x = pkbf(v[0], v[1]);
    u.y = pkbf(v[2], v[3]);
    u.z = pkbf(v[4], v[5]);
    u.w = pkbf(v[6], v[7]);
    return u;
}

// one K16 step: a-frag from registers (kg-selected), 2 b-reads, 2 MFMA
template<int C, int S>
__device__ __forceinline__ void kstep(const float (&x)[DIM], const uint4* bb,
                                      f32x16 (&acc)[2], int l, bool kgb, int cq)
{
    uint4 f0 = packFrag<C * 32 + S * 16 + 0>(x);   // k-group 0 (lanes 0-31)
    uint4 f1 = packFrag<C * 32 + S * 16 + 8>(x);   // k-group 1 (lanes 32-63)
    uint4 fs;
    fs.x = kgb ? f1.x : f0.x;
    fs.y = kgb ? f1.y : f0.y;
    fs.z = kgb ? f1.z : f0.z;
    fs.w = kgb ? f1.w : f0.w;
    short8 a = __builtin_bit_cast(short8, fs);
#pragma unroll
    for (int j = 0; j < 2; ++j) {
        short8 b = __builtin_bit_cast(short8, bb[(S * 8 + cq * 2 + j) * 64 + l]);
        acc[j] = __builtin_amdgcn_mfma_f32_32x32x16_bf16(a, b, acc[j], 0, 0, 0);
    }
}

template<int C>
__device__ __forceinline__ void doChunk(const float (&x)[DIM],
    uint4* sB4, const uint4* __restrict__ PsiF4, f32x16 (&acc)[2],
    int l, int w, bool kgb, int cq)
{
    // entry (prev barrier): DMA(C) landed in sB[C%3]; DMA(C+1) in flight or
    // landed; sB[(C+2)%3] free (its readers -- body C-1 -- sealed by barrier).

    // issue DMA(C+2); stays in flight across this body's end barrier
    if constexpr (C + 2 < NCH) {
        constexpr int NI = (C + 2 == 17) ? 1 : 2;   // chunk 17 is 512 granules
        const uint4* src = PsiF4 + (C + 2) * 1024 + w * 64 + l;
        uint4* dst = sB4 + ((C + 2) % 3) * 1024 + w * 64 + l;
#pragma unroll
        for (int i = 0; i < NI; ++i) dma16(src + i * 512, dst + i * 512);
    }

    const uint4* bb = sB4 + (C % 3) * 1024;
    kstep<C, 0>(x, bb, acc, l, kgb, cq);
    if constexpr (C < 17) kstep<C, 1>(x, bb, acc, l, kgb, cq);

    // end barrier: certify DMA(C+1) landed; allow DMA(C+2)'s loads to fly.
    if constexpr (C <= 14)      waitbar<2>();
    else if constexpr (C == 15) waitbar<1>();   // only chunk-17's 1 load flying
    else if constexpr (C == 16) waitbar<0>();   // nothing left to prefetch
    // C == 17: no barrier needed (no shared writes until epilogue overlay)
}

__global__ __launch_bounds__(512, 4) void gmm_mfma(
    const float* __restrict__ points,
    const unsigned short* __restrict__ PsiF,
    const float* __restrict__ kc2,
    const float* __restrict__ thr,
    float* __restrict__ out)
{
    __shared__ uint4 sB4[3072];          // 48 KB: B triple buffer (3 x 16 KB)
    // epilogue scratch overlaid on buffer 0 (safe: buf0 last read in body 15,
    // sealed by end-16 vmcnt(0) barrier): sM [64][4], sS [64][4]
    float (*sM)[4] = (float (*)[4])sB4;
    float (*sS)[4] = (float (*)[4])((float*)sB4 + 256);

    const int t = threadIdx.x;
    const int w = t >> 6, l = t & 63;
    const bool kgb = (l >= 32);                    // k-group of this lane
    const int rb2 = w >> 2, cq = w & 3;            // wave tile: 32r x 64c
    const int row = rb2 * 32 + (l & 31);           // the row THIS LANE feeds

    const uint4* PsiF4 = (const uint4*)PsiF;

    // prologue DMA: chunks 0 and 1 into buffers 0,1
    {
        const uint4* src = PsiF4 + w * 64 + l;
        uint4* dst = sB4 + w * 64 + l;
        dma16(src,        dst);
        dma16(src +  512, dst +  512);
        dma16(src + 1024, dst + 1024);
        dma16(src + 1536, dst + 1536);
    }

    // x of this lane's row (4 threads/row redundancy; L1-served)
    float x[DIM];
    const float4* px = (const float4*)(points + ((size_t)blockIdx.x * 64 + row) * DIM);
#pragma unroll
    for (int j2 = 0; j2 < 8; ++j2) {
        float4 v = px[j2];
        x[4 * j2 + 0] = v.x; x[4 * j2 + 1] = v.y;
        x[4 * j2 + 2] = v.z; x[4 * j2 + 3] = v.w;
    }

    f32x16 acc[2];
#pragma unroll
    for (int j = 0; j < 2; ++j)
#pragma unroll
        for (int r = 0; r < 16; ++r) acc[j][r] = 0.f;

    // prologue drain: chunk-0 (and x) certified; loop runs counted from here
    asm volatile("s_waitcnt vmcnt(0)\ns_barrier" ::: "memory");

    doChunk<0>(x, sB4, PsiF4, acc, l, w, kgb, cq);
    doChunk<1>(x, sB4, PsiF4, acc, l, w, kgb, cq);
    doChunk<2>(x, sB4, PsiF4, acc, l, w, kgb, cq);
    doChunk<3>(x, sB4, PsiF4, acc, l, w, kgb, cq);
    doChunk<4>(x, sB4, PsiF4, acc, l, w, kgb, cq);
    doChunk<5>(x, sB4, PsiF4, acc, l, w, kgb, cq);
    doChunk<6>(x, sB4, PsiF4, acc, l, w, kgb, cq);
    doChunk<7>(x, sB4, PsiF4, acc, l, w, kgb, cq);
    doChunk<8>(x, sB4, PsiF4, acc, l, w, kgb, cq);
    doChunk<9>(x, sB4, PsiF4, acc, l, w, kgb, cq);
    doChunk<10>(x, sB4, PsiF4, acc, l, w, kgb, cq);
    doChunk<11>(x, sB4, PsiF4, acc, l, w, kgb, cq);
    doChunk<12>(x, sB4, PsiF4, acc, l, w, kgb, cq);
    doChunk<13>(x, sB4, PsiF4, acc, l, w, kgb, cq);
    doChunk<14>(x, sB4, PsiF4, acc, l, w, kgb, cq);
    doChunk<15>(x, sB4, PsiF4, acc, l, w, kgb, cq);
    doChunk<16>(x, sB4, PsiF4, acc, l, w, kgb, cq);
    doChunk<17>(x, sB4, PsiF4, acc, l, w, kgb, cq);

    // epilogue: add kc2, row-wise LSE over 256 cols (four 64-col quarters)
    float kcv[2];
    kcv[0] = kc2[(cq * 2 + 0) * 32 + (l & 31)];
    kcv[1] = kc2[(cq * 2 + 1) * 32 + (l & 31)];

#pragma unroll
    for (int rg = 0; rg < 16; ++rg) {
        float v0 = acc[0][rg] + kcv[0];
        float v1 = acc[1][rg] + kcv[1];
        float m = fmaxf(v0, v1);
#pragma unroll
        for (int mask = 1; mask < 32; mask <<= 1) m = fmaxf(m, __shfl_xor(m, mask, 64));
        float sv = __expf(v0 - m) + __expf(v1 - m);
#pragma unroll
        for (int mask = 1; mask < 32; mask <<= 1) sv += __shfl_xor(sv, mask, 64);
        if ((l & 31) == 0) {
            const int R = rb2 * 32 + (rg & 3) + 8 * (rg >> 2) + 4 * (l >> 5);
            sM[R][cq] = m; sS[R][cq] = sv;
        }
    }
    __syncthreads();

    if (t < 64) {
        const float m0 = sM[t][0], m1 = sM[t][1], m2 = sM[t][2], m3 = sM[t][3];
        const float M = fmaxf(fmaxf(m0, m1), fmaxf(m2, m3));
        const float Sv = sS[t][0] * __expf(m0 - M) + sS[t][1] * __expf(m1 - M)
                       + sS[t][2] * __expf(m2 - M) + sS[t][3] * __expf(m3 - M);
        out[(size_t)blockIdx.x * 64 + t] = M + __logf(Sv) - thr[0];
    }
}

extern "C" void kernel_launch(void* const* d_in, const int* in_sizes, int n_in,
                              void* d_out, int out_size, void* d_ws, size_t ws_size,
                              hipStream_t stream) {
    const float* points  = (const float*)d_in[0];
    const float* centers = (const float*)d_in[1];
    const float* covs    = (const float*)d_in[2];
    const float* weights = (const float*)d_in[3];
    const float* thr     = (const float*)d_in[4];
    float* out = (float*)d_out;

    unsigned short* PsiF = (unsigned short*)d_ws;
    float* kc2 = (float*)((char*)d_ws + PSIF_BYTES);

    gmm_pre<<<KCOMP, 256, 0, stream>>>(covs, centers, weights, PsiF, kc2);
    gmm_mfma<<<NPTS / 64, 512, 0, stream>>>(points, PsiF, kc2, thr, out);
}

// Round 6
// 142.993 us; speedup vs baseline: 1.2585x; 1.2585x over previous
//
#include <hip/hip_runtime.h>
#include <math.h>

#define NPTS 131072
#define KCOMP 256
#define DIM 32
#define NREAL 560                 // 528 tight-packed quad + 32 linear
#define NCH 18                    // 32-feature chunks: 17 full + 1 half (16)
#define PSIF_BYTES 294912         // 18 chunks * 1024 granules * 16 B
#define WS_NEED (PSIF_BYTES + KCOMP * 4)

typedef __attribute__((ext_vector_type(8))) short short8;
typedef __attribute__((ext_vector_type(16))) float f32x16;

__device__ __forceinline__ unsigned short f2bf(float v) {
    unsigned u = __float_as_uint(v);
    u += 0x7fffu + ((u >> 16) & 1u);   // RNE
    return (unsigned short)(u >> 16);
}

// pack two f32 -> two bf16 (lo | hi<<16). RTN (+0x8000) + byte-perm: 3 ops.
__device__ __forceinline__ unsigned pkbf(float lo, float hi) {
#if __has_builtin(__builtin_amdgcn_perm)
    const unsigned a = __float_as_uint(hi) + 0x8000u;
    const unsigned b = __float_as_uint(lo) + 0x8000u;
    return __builtin_amdgcn_perm(a, b, 0x07060302u);
#else
    return (unsigned)f2bf(lo) | ((unsigned)f2bf(hi) << 16);
#endif
}

// async global->LDS DMA, 16 B/lane; LDS dest = wave-uniform base + lane*16.
__device__ __forceinline__ void dma16(const uint4* g, uint4* s) {
    __builtin_amdgcn_global_load_lds(
        (const __attribute__((address_space(1))) void*)g,
        (__attribute__((address_space(3))) void*)s, 16, 0, 0);
}

// counted-vmcnt barrier: newest N vmem ops (the just-issued prefetch) may
// stay in flight; everything older (previous chunk's DMA) must have landed.
// lgkmcnt(0) publishes this wave's gen ds_writes before the barrier.
template<int N>
__device__ __forceinline__ void waitbar() {
    if constexpr (N == 2)
        asm volatile("s_waitcnt vmcnt(2) lgkmcnt(0)\ns_barrier" ::: "memory");
    else if constexpr (N == 1)
        asm volatile("s_waitcnt vmcnt(1) lgkmcnt(0)\ns_barrier" ::: "memory");
    else
        asm volatile("s_waitcnt vmcnt(0) lgkmcnt(0)\ns_barrier" ::: "memory");
}

// ---- compile-time feature decode: TIGHT triangular packing ----------------
// p in [0,528): (d,f) pairs, f>=d, row-major (row d has 32-d entries).
// p in [528,560): linear features (index p-528).
constexpr int PfxT(int d) { return 32 * d - (d * (d - 1)) / 2; }
constexpr int rowT(int p) { int d = 0; while (d < 31 && PfxT(d + 1) <= p) ++d; return d; }
constexpr int colT(int p) { return rowT(p) + (p - PfxT(rowT(p))); }

template<int P, int J>
__device__ __forceinline__ float genOne(const float (&x)[DIM]) {
    constexpr int p = P + J;
    if constexpr (p >= NREAL) {
        return 0.f;
    } else if constexpr (p >= 528) {
        return x[p - 528];
    } else {
        constexpr int d = rowT(p);
        constexpr int f = colT(p);
        static_assert(d >= 0 && d < 32 && f >= d && f < 32, "bad feature map");
        return x[d] * x[f];
    }
}

// ---------------------------------------------------------------------------
// Precompute: Psi column k scattered into frag-ordered PsiF (bf16), kc2 fp32.
// ---------------------------------------------------------------------------
__global__ __launch_bounds__(256) void gmm_pre(
    const float* __restrict__ S,
    const float* __restrict__ centers,
    const float* __restrict__ weights,
    unsigned short* __restrict__ PsiF,
    float* __restrict__ kc2)
{
    __shared__ float Sl[DIM][DIM + 1];
    __shared__ float As[DIM][DIM + 1];
    __shared__ float cl[DIM], ml[DIM];
    __shared__ float red[256];

    const int k = blockIdx.x, tid = threadIdx.x;

    for (int idx = tid; idx < DIM * DIM; idx += 256)
        Sl[idx >> 5][idx & 31] = S[(size_t)k * DIM * DIM + idx];
    if (tid < DIM) cl[tid] = centers[k * DIM + tid];
    __syncthreads();

    // A = S S^T
    for (int idx = tid; idx < DIM * DIM; idx += 256) {
        const int d = idx >> 5, f = idx & 31;
        float a = 0.f;
#pragma unroll
        for (int e = 0; e < DIM; ++e) a = fmaf(Sl[d][e], Sl[f][e], a);
        As[d][f] = a;
    }
    __syncthreads();

    if (tid < DIM) {
        float mv = 0.f;
#pragma unroll
        for (int f = 0; f < DIM; ++f) mv = fmaf(As[tid][f], cl[f], mv);
        ml[tid] = mv;
    }
    __syncthreads();

    // scatter Psi column k into frag positions (reads As diag+upper, ml).
    for (int p = tid; p < NREAL; p += 256) {
        float val;
        if (p < 528) {
            int d = 0, pr = 0;
            while (pr + (32 - d) <= p) { pr += (32 - d); ++d; }
            const int f = d + (p - pr);
            val = (f == d) ? -0.5f * As[d][d] : -As[d][f];
        } else {
            val = ml[p - 528];
        }
        const int c = p >> 6, kk = p & 63;
        const int s = kk >> 4, qq = (kk >> 3) & 1, j = kk & 7;
        const int ct = k >> 5, ll = qq * 32 + (k & 31);
        const int g = c * 2048 + (s * 8 + ct) * 64 + ll;
        PsiF[(size_t)g * 8 + j] = f2bf(val);
    }

    red[tid] = fabsf(weights[tid]);          // K == 256 == blockDim
    __syncthreads();                          // also fences As/ml reads above
    for (int off = 128; off > 0; off >>= 1) {
        if (tid < off) red[tid] += red[tid + off];
        __syncthreads();
    }
    const float wsum = red[0];

    // SPD Gaussian elimination: 1 barrier/step, logdet(A) = sum log(pivot_j).
    for (int j = 0; j < DIM - 1; ++j) {
        const float inv = 1.0f / As[j][j];
        for (int idx = tid; idx < DIM * DIM; idx += 256) {
            const int r = idx >> 5, c = idx & 31;
            if (r > j && c > j)
                As[r][c] = fmaf(-As[r][j] * inv, As[j][c], As[r][c]);
        }
        __syncthreads();
    }

    if (tid < DIM) red[tid] = __logf(As[tid][tid]);   // pivots > 0 (SPD)
    __syncthreads();
    if (tid == 0) {
        float sl = 0.f;
        for (int j = 0; j < DIM; ++j) sl += red[j];
        float cac = 0.f;
        for (int d2 = 0; d2 < DIM; ++d2) cac = fmaf(ml[d2], cl[d2], cac);
        kc2[k] = __logf(fabsf(weights[k])) - __logf(wsum + 1e-30f)
               + 0.5f * sl - 0.5f * cac;
    }
}

// ---------------------------------------------------------------------------
// Main MFMA kernel v6 = R4 structure (LDS-amortized A-gen, 512 thr, 128-row
// block, wave tile 32r x 128c) + 3-deep B pipeline with counted-vmcnt
// barriers: body C issues DMA(C+2); end-C barrier waits vmcnt(2) so the
// fresh prefetch stays in flight (never vmcnt(0) in steady state) while
// DMA(C+1) -- issued a full body earlier -- is certified landed.
// LDS = sA 2x8 KB + sB 3x16 KB = 64 KB -> 2 blocks/CU (unchanged).
// ---------------------------------------------------------------------------
template<int P>
__device__ __forceinline__ void genQuad(const float (&x)[DIM], float* v) {
    v[0] = genOne<P, 0>(x);
    v[1] = genOne<P, 1>(x);
    v[2] = genOne<P, 2>(x);
    v[3] = genOne<P, 3>(x);
}

// site SS (8 features) of 32-feature chunk CH -> sA buffer (CH&1)
template<int CH, int SS>
__device__ __forceinline__ void genSite(const float (&x)[DIM], uint4* base,
                                        int rbg, int r32) {
    float v[8];
    genQuad<CH * 32 + SS * 8>(x, v);
    genQuad<CH * 32 + SS * 8 + 4>(x, v + 4);
    uint4 u;
    u.x = pkbf(v[0], v[1]);
    u.y = pkbf(v[2], v[3]);
    u.z = pkbf(v[4], v[5]);
    u.w = pkbf(v[6], v[7]);
    base[(SS >> 1) * 256 + rbg * 64 + (SS & 1) * 32 + r32] = u;
}

// q = t>>7 is wave-pair-uniform: each q handles one site -> no divergence.
template<int CH>
__device__ __forceinline__ void genChunk(const float (&x)[DIM], uint4* sA4,
                                         int q, int rbg, int r32) {
    uint4* base = sA4 + (CH & 1) * 512;
    if constexpr (CH < 17) {
        if (q == 0)      genSite<CH, 0>(x, base, rbg, r32);
        else if (q == 1) genSite<CH, 1>(x, base, rbg, r32);
        else if (q == 2) genSite<CH, 2>(x, base, rbg, r32);
        else             genSite<CH, 3>(x, base, rbg, r32);
    } else {
        if (q == 0)      genSite<CH, 0>(x, base, rbg, r32);
        else if (q == 1) genSite<CH, 1>(x, base, rbg, r32);
        // q >= 2 idle: chunk 17 has only 16 features (2 sites)
    }
}

template<int C>
__device__ __forceinline__ void doChunk(const float (&x)[DIM],
    uint4* sA4, uint4* sB4, const uint4* __restrict__ PsiF4,
    f32x16 (&acc)[4],
    int l, int w, int q, int rbg, int r32, int rb, int c0)
{
    // entry (prev barrier): DMA(C) landed in sB[C%3]; DMA(C+1) in flight;
    // gen(C) complete in sA[C&1]; sB[(C+2)%3] free (body C-1 readers sealed).

    // issue DMA(C+2); its loads stay in flight across this body's barrier
    if constexpr (C + 2 < NCH) {
        constexpr int NI = (C + 2 == 17) ? 1 : 2;   // chunk 17 is 512 granules
        const uint4* src = PsiF4 + (C + 2) * 1024 + w * 64 + l;
        uint4* dst = sB4 + ((C + 2) % 3) * 1024 + w * 64 + l;
#pragma unroll
        for (int i = 0; i < NI; ++i) dma16(src + i * 512, dst + i * 512);
    }

    // gen next chunk's A into the other sA buffer (VALU; overlaps MFMA below)
    if constexpr (C + 1 < NCH) genChunk<C + 1>(x, sA4, q, rbg, r32);

    // MFMA on current chunk: wave tile 32r x 128c
    constexpr int NS = (C < 17) ? 2 : 1;            // K16-steps in this chunk
    const uint4* aa = sA4 + (C & 1) * 512;
    const uint4* bb = sB4 + (C % 3) * 1024;
#pragma unroll
    for (int s = 0; s < NS; ++s) {
        short8 a = __builtin_bit_cast(short8, aa[(s * 4 + rb) * 64 + l]);
#pragma unroll
        for (int j = 0; j < 4; ++j) {
            short8 b = __builtin_bit_cast(short8, bb[(s * 8 + c0 + j) * 64 + l]);
            acc[j] = __builtin_amdgcn_mfma_f32_32x32x16_bf16(a, b, acc[j], 0, 0, 0);
        }
    }

    // end barrier: certify DMA(C+1); let DMA(C+2)'s NI(C+2) loads keep flying.
    if constexpr (C <= 14)      waitbar<2>();
    else if constexpr (C == 15) waitbar<1>();   // only chunk-17's 1 load flies
    else if constexpr (C == 16) waitbar<0>();   // drain: body 17 reads sB[2]
    // C == 17: no barrier (epilogue overlay is disjoint from body-17 reads)
}

__device__ __forceinline__ void epiHalf(const f32x16 (&acc)[4], const float (&kcv)[4],
    int rblock, int l, int whalf, float (*sM)[2], float (*sS)[2])
{
#pragma unroll
    for (int rg = 0; rg < 16; ++rg) {
        float vals[4], m = -INFINITY;
#pragma unroll
        for (int j = 0; j < 4; ++j) { vals[j] = acc[j][rg] + kcv[j]; m = fmaxf(m, vals[j]); }
#pragma unroll
        for (int mask = 1; mask < 32; mask <<= 1) m = fmaxf(m, __shfl_xor(m, mask, 64));
        float sv = 0.f;
#pragma unroll
        for (int j = 0; j < 4; ++j) sv += __expf(vals[j] - m);
#pragma unroll
        for (int mask = 1; mask < 32; mask <<= 1) sv += __shfl_xor(sv, mask, 64);
        if ((l & 31) == 0) {
            const int R = rblock * 32 + (rg & 3) + 8 * (rg >> 2) + 4 * (l >> 5);
            sM[R][whalf] = m; sS[R][whalf] = sv;
        }
    }
}

__global__ __launch_bounds__(512, 4) void gmm_mfma(
    const float* __restrict__ points,
    const unsigned short* __restrict__ PsiF,
    const float* __restrict__ kc2,
    const float* __restrict__ thr,
    float* __restrict__ out)
{
    __shared__ uint4 sA4[1024];          // 16 KB: A double buffer (2 x 8 KB)
    __shared__ uint4 sB4[3072];          // 48 KB: B triple buffer (3 x 16 KB)
    // epilogue scratch overlaid on sA4 buffer 0 (bytes 0..2K; body-17 reads
    // sA[1] bytes 8-16K + sB[2] -- disjoint): sM 1 KB, sS 1 KB
    float (*sM)[2] = (float (*)[2])sA4;
    float (*sS)[2] = (float (*)[2])(sA4 + 64);

    const int t = threadIdx.x;
    const int w = t >> 6, l = t & 63;
    const int row = t & 127, q = t >> 7;           // gen role: one site per q
    const int rbg = row >> 5, r32 = row & 31;
    const int rb = w >> 1, c0 = (w & 1) * 4;       // mfma wave tile: 32r x 128c

    const uint4* PsiF4 = (const uint4*)PsiF;

    // prologue DMA: chunk 0 -> sB[0], chunk 1 -> sB[1]
    {
        const uint4* src = PsiF4 + w * 64 + l;
        uint4* dst = sB4 + w * 64 + l;
        dma16(src,        dst);
        dma16(src +  512, dst +  512);
        dma16(src + 1024, dst + 1024);
        dma16(src + 1536, dst + 1536);
    }

    float x[DIM];
    const float4* px = (const float4*)(points + ((size_t)blockIdx.x * 128 + row) * DIM);
#pragma unroll
    for (int j2 = 0; j2 < 8; ++j2) {
        float4 v = px[j2];
        x[4 * j2 + 0] = v.x; x[4 * j2 + 1] = v.y;
        x[4 * j2 + 2] = v.z; x[4 * j2 + 3] = v.w;
    }

    f32x16 acc[4];
#pragma unroll
    for (int j = 0; j < 4; ++j)
#pragma unroll
        for (int r = 0; r < 16; ++r) acc[j][r] = 0.f;

    genChunk<0>(x, sA4, q, rbg, r32);
    __syncthreads();   // one-time full drain: chunk 0+1 DMA, x, gen(0) ready

    doChunk<0>(x, sA4, sB4, PsiF4, acc, l, w, q, rbg, r32, rb, c0);
    doChunk<1>(x, sA4, sB4, PsiF4, acc, l, w, q, rbg, r32, rb, c0);
    doChunk<2>(x, sA4, sB4, PsiF4, acc, l, w, q, rbg, r32, rb, c0);
    doChunk<3>(x, sA4, sB4, PsiF4, acc, l, w, q, rbg, r32, rb, c0);
    doChunk<4>(x, sA4, sB4, PsiF4, acc, l, w, q, rbg, r32, rb, c0);
    doChunk<5>(x, sA4, sB4, PsiF4, acc, l, w, q, rbg, r32, rb, c0);
    doChunk<6>(x, sA4, sB4, PsiF4, acc, l, w, q, rbg, r32, rb, c0);
    doChunk<7>(x, sA4, sB4, PsiF4, acc, l, w, q, rbg, r32, rb, c0);
    doChunk<8>(x, sA4, sB4, PsiF4, acc, l, w, q, rbg, r32, rb, c0);
    doChunk<9>(x, sA4, sB4, PsiF4, acc, l, w, q, rbg, r32, rb, c0);
    doChunk<10>(x, sA4, sB4, PsiF4, acc, l, w, q, rbg, r32, rb, c0);
    doChunk<11>(x, sA4, sB4, PsiF4, acc, l, w, q, rbg, r32, rb, c0);
    doChunk<12>(x, sA4, sB4, PsiF4, acc, l, w, q, rbg, r32, rb, c0);
    doChunk<13>(x, sA4, sB4, PsiF4, acc, l, w, q, rbg, r32, rb, c0);
    doChunk<14>(x, sA4, sB4, PsiF4, acc, l, w, q, rbg, r32, rb, c0);
    doChunk<15>(x, sA4, sB4, PsiF4, acc, l, w, q, rbg, r32, rb, c0);
    doChunk<16>(x, sA4, sB4, PsiF4, acc, l, w, q, rbg, r32, rb, c0);
    doChunk<17>(x, sA4, sB4, PsiF4, acc, l, w, q, rbg, r32, rb, c0);

    // epilogue: add kc2, row-wise LSE over 256 cols (two 128-col halves)
    float kcv[4];
#pragma unroll
    for (int j = 0; j < 4; ++j) kcv[j] = kc2[(c0 + j) * 32 + (l & 31)];

    epiHalf(acc, kcv, rb, l, w & 1, sM, sS);
    __syncthreads();

    if (t < 128) {
        const float m0 = sM[t][0], m1 = sM[t][1];
        const float M = fmaxf(m0, m1);
        const float Sv = sS[t][0] * __expf(m0 - M) + sS[t][1] * __expf(m1 - M);
        out[(size_t)blockIdx.x * 128 + t] = M + __logf(Sv) - thr[0];
    }
}

extern "C" void kernel_launch(void* const* d_in, const int* in_sizes, int n_in,
                              void* d_out, int out_size, void* d_ws, size_t ws_size,
                              hipStream_t stream) {
    const float* points  = (const float*)d_in[0];
    const float* centers = (const float*)d_in[1];
    const float* covs    = (const float*)d_in[2];
    const float* weights = (const float*)d_in[3];
    const float* thr     = (const float*)d_in[4];
    float* out = (float*)d_out;

    unsigned short* PsiF = (unsigned short*)d_ws;
    float* kc2 = (float*)((char*)d_ws + PSIF_BYTES);

    gmm_pre<<<KCOMP, 256, 0, stream>>>(covs, centers, weights, PsiF, kc2);
    gmm_mfma<<<NPTS / 128, 512, 0, stream>>>(points, PsiF, kc2, thr, out);
}